// Round 6
// baseline (414.938 us; speedup 1.0000x reference)
//
#include <hip/hip_runtime.h>
#include <hip/hip_cooperative_groups.h>
#include <hip/hip_bf16.h>
#include <math.h>

namespace cg = cooperative_groups;

#define N_DIM 1024
#define C_DIM 256
#define CN (C_DIM * N_DIM)
#define TOT (8 * CN)
#define BN_EPS 1e-5f
#define SCALE 0.1f

typedef short short8 __attribute__((ext_vector_type(8)));
typedef float f32x4 __attribute__((ext_vector_type(4)));

__device__ __forceinline__ float mspike(float x) {
    return rintf(fminf(fmaxf(x, 0.f), 4.f)) * 0.25f;
}
__device__ __forceinline__ unsigned short bfbits(float x) {
    __hip_bfloat16 h = __float2bfloat16(x);
    return *reinterpret_cast<unsigned short*>(&h);
}
__device__ __forceinline__ f32x4 mfma16(short8 a, short8 b, f32x4 c) {
    return __builtin_amdgcn_mfma_f32_16x16x32_bf16(a, b, c, 0, 0, 0);
}
__device__ __forceinline__ void async16(void* lds, const void* g) {
    __builtin_amdgcn_global_load_lds(
        (const __attribute__((address_space(1))) void*)g,
        (__attribute__((address_space(3))) void*)lds, 16, 0, 0);
}

struct SMemG { short At[2][128 * 64]; short Bt[2][2][64 * 64]; };  // 64 KB
struct SMemP { float ld[64][65]; };
struct SMemA { float pbuf[4][32][33]; unsigned short aop[64][32]; };
union SMem { SMemG g; SMemP p; SMemA a; };

// ============================ phase 1: prep =================================
__device__ __forceinline__ void phase_prep(
    SMemP& sp, int bz, int t,
    const float* __restrict__ q, const float* __restrict__ qp,
    const float* __restrict__ w, const float* __restrict__ cb,
    const float* __restrict__ g, const float* __restrict__ bet,
    const float* __restrict__ mn, const float* __restrict__ vr,
    float* __restrict__ tmp, unsigned short* __restrict__ sxT,
    unsigned short* __restrict__ whl, float* __restrict__ bninv,
    float* __restrict__ bnsh) {
    int logical = ((bz & 7) << 6) + (bz >> 3);
    {
        int tb = logical >> 6, u = logical & 63;
        int c0 = (u >> 4) * 64, n0 = (u & 15) * 64;
        int cl = t >> 4, nl = (t & 15) * 4;
        size_t base = (size_t)tb * CN;
#pragma unroll
        for (int r = 0; r < 4; ++r) {
            int c = cl + r * 16;
            size_t off = base + (size_t)(c0 + c) * N_DIM + n0 + nl;
            float4 a = *(const float4*)&q[off];
            float4 b = *(const float4*)&qp[off];
            float4 s = make_float4(a.x + b.x, a.y + b.y, a.z + b.z, a.w + b.w);
            *(float4*)&tmp[off] = s;
            sp.ld[c][nl] = mspike(s.x); sp.ld[c][nl + 1] = mspike(s.y);
            sp.ld[c][nl + 2] = mspike(s.z); sp.ld[c][nl + 3] = mspike(s.w);
        }
        __syncthreads();
        int nl2 = t >> 2, cg2 = (t & 3) * 16;
        size_t ob = base + (size_t)(n0 + nl2) * C_DIM + c0 + cg2;
#pragma unroll
        for (int j = 0; j < 8; ++j) {
            ushort2 u2 = make_ushort2(bfbits(sp.ld[cg2 + 2 * j][nl2]),
                                      bfbits(sp.ld[cg2 + 2 * j + 1][nl2]));
            *(ushort2*)&sxT[ob + 2 * j] = u2;
        }
    }
    {
        int row = 2 * logical + (t >> 7);
        int tl = t & 127;
        float2 wv = *(const float2*)&w[(size_t)row * 256 + tl * 2];
        __hip_bfloat16 h0 = __float2bfloat16(wv.x);
        __hip_bfloat16 h1 = __float2bfloat16(wv.y);
        __hip_bfloat16 l0 = __float2bfloat16(wv.x - __bfloat162float(h0));
        __hip_bfloat16 l1 = __float2bfloat16(wv.y - __bfloat162float(h1));
        size_t base = (size_t)row * 512;
        *(ushort2*)&whl[base + tl * 2] =
            make_ushort2(*(unsigned short*)&h0, *(unsigned short*)&h1);
        *(ushort2*)&whl[base + 256 + tl * 2] =
            make_ushort2(*(unsigned short*)&l0, *(unsigned short*)&l1);
        if (tl == 0) {
            float inv = g[row] / sqrtf(vr[row] + BN_EPS);
            bninv[row] = inv;
            bnsh[row] = (cb[row] - mn[row]) * inv + bet[row];
        }
    }
}

// ===================== phase 2 / 4: conv GEMMs ==============================
template <int FIN>
__device__ __forceinline__ void phase_conv(
    SMemG& sg, int bz,
    const unsigned short* __restrict__ whl,
    const unsigned short* __restrict__ actT,
    const float* __restrict__ bninv, const float* __restrict__ bnsh,
    unsigned short* __restrict__ dq, unsigned short* __restrict__ dk,
    unsigned short* __restrict__ dv, const float* __restrict__ tmp,
    float* __restrict__ outf) {
    int tb, m0, n0;
    bool isQ = false;
    if (FIN) {
        int logical = ((bz & 7) << 5) + (bz >> 3);
        tb = logical >> 5;
        int u = logical & 31;
        m0 = (u >> 2) * 128; n0 = (u & 3) * 64;
    } else {
        int logical = ((bz & 7) << 6) + (bz >> 3);
        tb = logical >> 6;
        int u = logical & 63;
        if (u < 32) { isQ = true; m0 = ((u >> 4) & 1) * 128; n0 = (u & 15) * 64; }
        else { u -= 32; m0 = (u >> 2) * 128; n0 = (u & 3) * 64; }
    }
    const int tid = threadIdx.x, lane = tid & 63, wid = tid >> 6;
    const int wm = wid >> 1, wn = wid & 1;
    const int l15 = lane & 15, l4 = lane >> 4;
    const unsigned short* abase = actT + (size_t)tb * CN;
    f32x4 z = {0.f, 0.f, 0.f, 0.f};

    if (!FIN && isQ) {
        const unsigned short* pa[4];
        const unsigned short* pb[2];
#pragma unroll
        for (int c = 0; c < 4; ++c) {
            int s = c * 256 + tid, row = s >> 3, gsw = ((s & 7) ^ (row & 7)) * 8;
            pa[c] = whl + (size_t)(m0 + row) * 512 + gsw;
        }
#pragma unroll
        for (int c = 0; c < 2; ++c) {
            int s = c * 256 + tid, row = s >> 3, gsw = ((s & 7) ^ (row & 7)) * 8;
            pb[c] = abase + (size_t)(n0 + row) * 256 + gsw;
        }
        f32x4 acc[4][2];
#pragma unroll
        for (int i = 0; i < 4; ++i) { acc[i][0] = z; acc[i][1] = z; }
        auto stage = [&](int buf, int kt) {
            int kw = kt * 64, ka = (kt & 3) * 64;
#pragma unroll
            for (int c = 0; c < 4; ++c)
                async16(&sg.At[buf][(c * 256 + tid) * 8], pa[c] + kw);
#pragma unroll
            for (int c = 0; c < 2; ++c)
                async16(&sg.Bt[buf][0][(c * 256 + tid) * 8], pb[c] + ka);
        };
        stage(0, 0);
        __syncthreads();
        int cur = 0;
        for (int kt = 0; kt < 8; ++kt) {
            if (kt < 7) stage(cur ^ 1, kt + 1);
#pragma unroll
            for (int kk = 0; kk < 2; ++kk) {
                short8 af[4], bf[2];
#pragma unroll
                for (int f = 0; f < 4; ++f) {
                    int rowa = wm * 64 + f * 16 + l15;
                    int ka = ((kk * 4 + l4) ^ (rowa & 7)) << 4;
                    af[f] = *(const short8*)((const char*)&sg.At[cur][0] + rowa * 128 + ka);
                }
#pragma unroll
                for (int f = 0; f < 2; ++f) {
                    int rowb = wn * 32 + f * 16 + l15;
                    int kb2 = ((kk * 4 + l4) ^ (rowb & 7)) << 4;
                    bf[f] = *(const short8*)((const char*)&sg.Bt[cur][0][0] + rowb * 128 + kb2);
                }
#pragma unroll
                for (int i = 0; i < 4; ++i) {
                    acc[i][0] = mfma16(af[i], bf[0], acc[i][0]);
                    acc[i][1] = mfma16(af[i], bf[1], acc[i][1]);
                }
            }
            __syncthreads();
            cur ^= 1;
        }
#pragma unroll
        for (int i = 0; i < 4; ++i) {
            int cb4 = m0 + wm * 64 + i * 16 + l4 * 4;
            float4 inv = *(const float4*)&bninv[cb4];
            float4 sh = *(const float4*)&bnsh[cb4];
#pragma unroll
            for (int j = 0; j < 2; ++j) {
                int n = n0 + wn * 32 + j * 16 + l15;
                f32x4 a = acc[i][j];
                ushort4 u4;
                u4.x = bfbits(mspike(a[0] * inv.x + sh.x));
                u4.y = bfbits(mspike(a[1] * inv.y + sh.y));
                u4.z = bfbits(mspike(a[2] * inv.z + sh.z));
                u4.w = bfbits(mspike(a[3] * inv.w + sh.w));
                *(ushort4*)&dq[(size_t)tb * CN + (size_t)n * C_DIM + cb4] = u4;
            }
        }
    } else {
        const int NB = FIN ? 1 : 2;
        const int brbase = FIN ? 3 : 1;
        const unsigned short* pa[4];
        const unsigned short* pb[2][2];
#pragma unroll
        for (int c = 0; c < 4; ++c) {
            int s = c * 256 + tid, row = s >> 3, gsw = ((s & 7) ^ (row & 7)) * 8;
            pa[c] = abase + (size_t)(m0 + row) * 256 + gsw;
        }
#pragma unroll
        for (int b = 0; b < NB; ++b)
#pragma unroll
            for (int c = 0; c < 2; ++c) {
                int s = c * 256 + tid, row = s >> 3, gsw = ((s & 7) ^ (row & 7)) * 8;
                pb[b][c] = whl + (size_t)(brbase + b) * 131072 +
                           (size_t)(n0 + row) * 512 + gsw;
            }
        f32x4 acc[2][4][2];
#pragma unroll
        for (int b = 0; b < NB; ++b)
#pragma unroll
            for (int i = 0; i < 4; ++i) { acc[b][i][0] = z; acc[b][i][1] = z; }
        auto stage = [&](int buf, int kt) {
            int kw = kt * 64, ka = (kt & 3) * 64;
#pragma unroll
            for (int c = 0; c < 4; ++c)
                async16(&sg.At[buf][(c * 256 + tid) * 8], pa[c] + ka);
#pragma unroll
            for (int b = 0; b < NB; ++b)
#pragma unroll
                for (int c = 0; c < 2; ++c)
                    async16(&sg.Bt[buf][b][(c * 256 + tid) * 8], pb[b][c] + kw);
        };
        stage(0, 0);
        __syncthreads();
        int cur = 0;
        for (int kt = 0; kt < 8; ++kt) {
            if (kt < 7) stage(cur ^ 1, kt + 1);
#pragma unroll
            for (int kk = 0; kk < 2; ++kk) {
                short8 af[4];
#pragma unroll
                for (int f = 0; f < 4; ++f) {
                    int rowa = wm * 64 + f * 16 + l15;
                    int ka = ((kk * 4 + l4) ^ (rowa & 7)) << 4;
                    af[f] = *(const short8*)((const char*)&sg.At[cur][0] + rowa * 128 + ka);
                }
#pragma unroll
                for (int b = 0; b < NB; ++b) {
                    short8 bf[2];
#pragma unroll
                    for (int f = 0; f < 2; ++f) {
                        int rowb = wn * 32 + f * 16 + l15;
                        int kb2 = ((kk * 4 + l4) ^ (rowb & 7)) << 4;
                        bf[f] = *(const short8*)((const char*)&sg.Bt[cur][b][0] + rowb * 128 + kb2);
                    }
#pragma unroll
                    for (int i = 0; i < 4; ++i) {
                        acc[b][i][0] = mfma16(af[i], bf[0], acc[b][i][0]);
                        acc[b][i][1] = mfma16(af[i], bf[1], acc[b][i][1]);
                    }
                }
            }
            __syncthreads();
            cur ^= 1;
        }
#pragma unroll
        for (int b = 0; b < NB; ++b) {
#pragma unroll
            for (int j = 0; j < 2; ++j) {
                int c = n0 + wn * 32 + j * 16 + l15;
                float inv = bninv[(brbase + b) * 256 + c];
                float sh = bnsh[(brbase + b) * 256 + c];
#pragma unroll
                for (int i = 0; i < 4; ++i) {
                    int nb4 = m0 + wm * 64 + i * 16 + l4 * 4;
                    f32x4 a = acc[b][i][j];
                    size_t off = (size_t)tb * CN + (size_t)c * N_DIM + nb4;
                    if (!FIN) {
                        ushort4 u4;
                        u4.x = bfbits(mspike(a[0] * inv + sh));
                        u4.y = bfbits(mspike(a[1] * inv + sh));
                        u4.z = bfbits(mspike(a[2] * inv + sh));
                        u4.w = bfbits(mspike(a[3] * inv + sh));
                        unsigned short* dst = (b == 0) ? dk : dv;
                        *(ushort4*)&dst[off] = u4;
                    } else {
                        float4 t4 = *(const float4*)&tmp[off];
                        float4 o;
                        o.x = a[0] * inv + sh + t4.x;
                        o.y = a[1] * inv + sh + t4.y;
                        o.z = a[2] * inv + sh + t4.z;
                        o.w = a[3] * inv + sh + t4.w;
                        *(float4*)&outf[off] = o;
                    }
                }
            }
        }
    }
}

// ======================== phase 3: attention ================================
__device__ __forceinline__ void phase_attn(
    SMemA& sa, int bz,
    const unsigned short* __restrict__ skD, const unsigned short* __restrict__ svD,
    const unsigned short* __restrict__ sqT, unsigned short* __restrict__ soT) {
    int logical = ((bz & 7) << 5) + (bz >> 3);
    int tb = logical >> 5, u = logical & 31;
    int h = u >> 2, nc = u & 3;
    int tid = threadIdx.x, lane = tid & 63, w = tid >> 6;
    int l15 = lane & 15, l4 = lane >> 4;
    const unsigned short* kb = skD + (size_t)tb * CN + (size_t)h * 32 * N_DIM;
    const unsigned short* vb = svD + (size_t)tb * CN + (size_t)h * 32 * N_DIM;
    f32x4 z = {0.f, 0.f, 0.f, 0.f};

    f32x4 acc[2][2];
    acc[0][0] = z; acc[0][1] = z; acc[1][0] = z; acc[1][1] = z;
    for (int ks = 0; ks < 8; ++ks) {
        int n0 = w * 256 + ks * 32 + l4 * 8;
        short8 a0 = *(const short8*)&kb[(size_t)l15 * N_DIM + n0];
        short8 a1 = *(const short8*)&kb[(size_t)(16 + l15) * N_DIM + n0];
        short8 b0 = *(const short8*)&vb[(size_t)l15 * N_DIM + n0];
        short8 b1 = *(const short8*)&vb[(size_t)(16 + l15) * N_DIM + n0];
        acc[0][0] = mfma16(a0, b0, acc[0][0]);
        acc[0][1] = mfma16(a0, b1, acc[0][1]);
        acc[1][0] = mfma16(a1, b0, acc[1][0]);
        acc[1][1] = mfma16(a1, b1, acc[1][1]);
    }
#pragma unroll
    for (int i = 0; i < 2; ++i)
#pragma unroll
        for (int j = 0; j < 2; ++j)
#pragma unroll
            for (int r = 0; r < 4; ++r)
                sa.pbuf[w][i * 16 + l4 * 4 + r][j * 16 + l15] = acc[i][j][r];
    __syncthreads();
    {
        int d1 = tid >> 3, d2 = (tid & 7) * 4;
        float4 s = make_float4(0.f, 0.f, 0.f, 0.f);
#pragma unroll
        for (int ww = 0; ww < 4; ++ww) {
            float4 p = *(const float4*)&sa.pbuf[ww][d1][d2];
            s.x += p.x; s.y += p.y; s.z += p.z; s.w += p.w;
        }
        float xs[4] = {s.x, s.y, s.z, s.w};
#pragma unroll
        for (int q4 = 0; q4 < 4; ++q4) {
            __hip_bfloat16 hh = __float2bfloat16(xs[q4]);
            float hf = __bfloat162float(hh);
            __hip_bfloat16 ll = __float2bfloat16(xs[q4] - hf);
            sa.aop[d1][d2 + q4] = *(unsigned short*)&hh;
            sa.aop[32 + d1][d2 + q4] = *(unsigned short*)&ll;
        }
    }
    __syncthreads();
    short8 afr[2][2];
#pragma unroll
    for (int kk = 0; kk < 2; ++kk)
#pragma unroll
        for (int fm = 0; fm < 2; ++fm) {
            short8 v;
#pragma unroll
            for (int i = 0; i < 8; ++i)
                v[i] = (short)sa.aop[kk * 32 + l4 * 8 + i][fm * 16 + l15];
            afr[kk][fm] = v;
        }
    const unsigned short* qb = sqT + (size_t)tb * CN;
    unsigned short* ob = soT + (size_t)tb * CN;
#pragma unroll
    for (int fn = 0; fn < 4; ++fn) {
        int n = nc * 256 + w * 64 + fn * 16 + l15;
        short8 bq = *(const short8*)&qb[(size_t)n * C_DIM + h * 32 + l4 * 8];
        f32x4 o0 = z, o1 = z;
        o0 = mfma16(afr[0][0], bq, o0);
        o0 = mfma16(afr[1][0], bq, o0);
        o1 = mfma16(afr[0][1], bq, o1);
        o1 = mfma16(afr[1][1], bq, o1);
        ushort4 u0, u1;
        u0.x = bfbits(mspike(SCALE * o0[0]));
        u0.y = bfbits(mspike(SCALE * o0[1]));
        u0.z = bfbits(mspike(SCALE * o0[2]));
        u0.w = bfbits(mspike(SCALE * o0[3]));
        u1.x = bfbits(mspike(SCALE * o1[0]));
        u1.y = bfbits(mspike(SCALE * o1[1]));
        u1.z = bfbits(mspike(SCALE * o1[2]));
        u1.w = bfbits(mspike(SCALE * o1[3]));
        size_t obase = (size_t)n * C_DIM + h * 32 + l4 * 4;
        *(ushort4*)&ob[obase] = u0;
        *(ushort4*)&ob[obase + 16] = u1;
    }
}

// ============================ mega kernel (coop) ============================
__global__ __launch_bounds__(256, 2) void mega_kernel(
    const float* __restrict__ query, const float* __restrict__ qpos,
    const float* __restrict__ convw, const float* __restrict__ convb,
    const float* __restrict__ gam, const float* __restrict__ bet,
    const float* __restrict__ mn, const float* __restrict__ vr,
    float* __restrict__ tmp, unsigned short* __restrict__ sxT,
    unsigned short* __restrict__ whl, float* __restrict__ bninv,
    float* __restrict__ bnsh, unsigned short* __restrict__ sqT,
    unsigned short* __restrict__ skD, unsigned short* __restrict__ svD,
    unsigned short* __restrict__ soT, float* __restrict__ outf) {
    __shared__ SMem sm;
    cg::grid_group grid = cg::this_grid();
    int bz = blockIdx.x, t = threadIdx.x;

    phase_prep(sm.p, bz, t, query, qpos, convw, convb, gam, bet, mn, vr,
               tmp, sxT, whl, bninv, bnsh);
    __threadfence();
    grid.sync();

    phase_conv<0>(sm.g, bz, whl, sxT, bninv, bnsh, sqT, skD, svD,
                  nullptr, nullptr);
    __threadfence();
    grid.sync();

    if (bz < 256)
        phase_attn(sm.a, bz, skD, svD, sqT, soT);
    __threadfence();
    grid.sync();

    if (bz < 256)
        phase_conv<1>(sm.g, bz, whl, soT, bninv, bnsh, nullptr, nullptr,
                      nullptr, tmp, outf);
}

// ====================== fallback standalone kernels =========================
__global__ __launch_bounds__(256) void k_prep(
    const float* __restrict__ query, const float* __restrict__ qpos,
    const float* __restrict__ convw, const float* __restrict__ convb,
    const float* __restrict__ gam, const float* __restrict__ bet,
    const float* __restrict__ mn, const float* __restrict__ vr,
    float* __restrict__ tmp, unsigned short* __restrict__ sxT,
    unsigned short* __restrict__ whl, float* __restrict__ bninv,
    float* __restrict__ bnsh) {
    __shared__ SMemP sp;
    phase_prep(sp, blockIdx.x, threadIdx.x, query, qpos, convw, convb,
               gam, bet, mn, vr, tmp, sxT, whl, bninv, bnsh);
}
__global__ __launch_bounds__(256) void k_conv0(
    const unsigned short* __restrict__ whl, const unsigned short* __restrict__ actT,
    const float* __restrict__ bninv, const float* __restrict__ bnsh,
    unsigned short* __restrict__ dq, unsigned short* __restrict__ dk,
    unsigned short* __restrict__ dv) {
    __shared__ SMemG sg;
    phase_conv<0>(sg, blockIdx.x, whl, actT, bninv, bnsh, dq, dk, dv,
                  nullptr, nullptr);
}
__global__ __launch_bounds__(256) void k_attn(
    const unsigned short* __restrict__ skD, const unsigned short* __restrict__ svD,
    const unsigned short* __restrict__ sqT, unsigned short* __restrict__ soT) {
    __shared__ SMemA sa;
    phase_attn(sa, blockIdx.x, skD, svD, sqT, soT);
}
__global__ __launch_bounds__(256) void k_conv1(
    const unsigned short* __restrict__ whl, const unsigned short* __restrict__ actT,
    const float* __restrict__ bninv, const float* __restrict__ bnsh,
    const float* __restrict__ tmp, float* __restrict__ outf) {
    __shared__ SMemG sg;
    phase_conv<1>(sg, blockIdx.x, whl, actT, bninv, bnsh, nullptr, nullptr,
                  nullptr, tmp, outf);
}

extern "C" void kernel_launch(void* const* d_in, const int* in_sizes, int n_in,
                              void* d_out, int out_size, void* d_ws, size_t ws_size,
                              hipStream_t stream) {
    const float* query = (const float*)d_in[0];
    const float* qpos  = (const float*)d_in[3];
    const float* convw = (const float*)d_in[4];
    const float* convb = (const float*)d_in[5];
    const float* gam   = (const float*)d_in[6];
    const float* bet   = (const float*)d_in[7];
    const float* mn    = (const float*)d_in[8];
    const float* vr    = (const float*)d_in[9];
    float* out = (float*)d_out;

    char* ws = (char*)d_ws;
    float* tmp = (float*)ws;
    unsigned short* sxT = (unsigned short*)(ws + (size_t)TOT * 4);
    unsigned short* sqT = sxT + TOT;
    unsigned short* skD = sqT + TOT;
    unsigned short* svD = skD + TOT;
    unsigned short* soT = svD + TOT;
    unsigned short* whl = soT + TOT;
    float* bninv = (float*)(whl + 4 * 256 * 512);
    float* bnsh = bninv + 1024;

    void* args[] = {
        (void*)&query, (void*)&qpos, (void*)&convw, (void*)&convb,
        (void*)&gam, (void*)&bet, (void*)&mn, (void*)&vr,
        (void*)&tmp, (void*)&sxT, (void*)&whl, (void*)&bninv, (void*)&bnsh,
        (void*)&sqT, (void*)&skD, (void*)&svD, (void*)&soT, (void*)&out};
    hipError_t ce = hipLaunchCooperativeKernel(
        reinterpret_cast<void*>(mega_kernel), dim3(512), dim3(256), args, 0,
        stream);
    if (ce != hipSuccess) {
        // Deterministic fallback: identical phase code as 4 plain launches.
        k_prep<<<512, 256, 0, stream>>>(query, qpos, convw, convb, gam, bet,
                                        mn, vr, tmp, sxT, whl, bninv, bnsh);
        k_conv0<<<512, 256, 0, stream>>>(whl, sxT, bninv, bnsh, sqT, skD, svD);
        k_attn<<<256, 256, 0, stream>>>(skD, svD, sqT, soT);
        k_conv1<<<256, 256, 0, stream>>>(whl, soT, bninv, bnsh, tmp, out);
    }
}

// Round 7
// 43.639 us; speedup vs baseline: 9.5083x; 9.5083x over previous
//
#include <hip/hip_runtime.h>
#include <hip/hip_bf16.h>
#include <math.h>

#define N_DIM 1024
#define C_DIM 256
#define CN (C_DIM * N_DIM)
#define TOT (8 * CN)
#define BN_EPS 1e-5f
#define SCALE 0.1f

typedef short short8 __attribute__((ext_vector_type(8)));
typedef float f32x4 __attribute__((ext_vector_type(4)));

__device__ __forceinline__ float mspike(float x) {
    return rintf(fminf(fmaxf(x, 0.f), 4.f)) * 0.25f;
}
__device__ __forceinline__ unsigned short bfbits(float x) {
    __hip_bfloat16 h = __float2bfloat16(x);
    return *reinterpret_cast<unsigned short*>(&h);
}
__device__ __forceinline__ f32x4 mfma16(short8 a, short8 b, f32x4 c) {
    return __builtin_amdgcn_mfma_f32_16x16x32_bf16(a, b, c, 0, 0, 0);
}
__device__ __forceinline__ void async16(void* lds, const void* g) {
    __builtin_amdgcn_global_load_lds(
        (const __attribute__((address_space(1))) void*)g,
        (__attribute__((address_space(3))) void*)lds, 16, 0, 0);
}

// ---- L1 (512 blocks): add+spike+transpose + 2 weight rows per block -------
__global__ __launch_bounds__(256) void prep_spike_kernel(
    const float* __restrict__ q, const float* __restrict__ qp,
    const float* __restrict__ w, const float* __restrict__ cb,
    const float* __restrict__ g, const float* __restrict__ bet,
    const float* __restrict__ mn, const float* __restrict__ vr,
    float* __restrict__ tmp, unsigned short* __restrict__ sxT,
    unsigned short* __restrict__ whl, float* __restrict__ bninv,
    float* __restrict__ bnsh) {
    int logical = ((blockIdx.x & 7) << 6) + (blockIdx.x >> 3);
    int t = threadIdx.x;
    __shared__ float ld[64][65];
    {
        int tb = logical >> 6, u = logical & 63;
        int c0 = (u >> 4) * 64, n0 = (u & 15) * 64;
        int cl = t >> 4, nl = (t & 15) * 4;
        size_t base = (size_t)tb * CN;
#pragma unroll
        for (int r = 0; r < 4; ++r) {
            int c = cl + r * 16;
            size_t off = base + (size_t)(c0 + c) * N_DIM + n0 + nl;
            float4 a = *(const float4*)&q[off];
            float4 b = *(const float4*)&qp[off];
            float4 s = make_float4(a.x + b.x, a.y + b.y, a.z + b.z, a.w + b.w);
            *(float4*)&tmp[off] = s;
            ld[c][nl] = mspike(s.x); ld[c][nl + 1] = mspike(s.y);
            ld[c][nl + 2] = mspike(s.z); ld[c][nl + 3] = mspike(s.w);
        }
        __syncthreads();
        int nl2 = t >> 2, cg2 = (t & 3) * 16;
        size_t ob = base + (size_t)(n0 + nl2) * C_DIM + c0 + cg2;
#pragma unroll
        for (int j = 0; j < 8; ++j) {
            ushort2 u2 = make_ushort2(bfbits(ld[cg2 + 2 * j][nl2]),
                                      bfbits(ld[cg2 + 2 * j + 1][nl2]));
            *(ushort2*)&sxT[ob + 2 * j] = u2;
        }
    }
    {
        int row = 2 * logical + (t >> 7);
        int tl = t & 127;
        float2 wv = *(const float2*)&w[(size_t)row * 256 + tl * 2];
        __hip_bfloat16 h0 = __float2bfloat16(wv.x);
        __hip_bfloat16 h1 = __float2bfloat16(wv.y);
        __hip_bfloat16 l0 = __float2bfloat16(wv.x - __bfloat162float(h0));
        __hip_bfloat16 l1 = __float2bfloat16(wv.y - __bfloat162float(h1));
        size_t base = (size_t)row * 512;
        *(ushort2*)&whl[base + tl * 2] =
            make_ushort2(*(unsigned short*)&h0, *(unsigned short*)&h1);
        *(ushort2*)&whl[base + 256 + tl * 2] =
            make_ushort2(*(unsigned short*)&l0, *(unsigned short*)&l1);
        if (tl == 0) {
            float inv = g[row] / sqrtf(vr[row] + BN_EPS);
            bninv[row] = inv;
            bnsh[row] = (cb[row] - mn[row]) * inv + bet[row];
        }
    }
}

// ---- conv GEMM, uniform 128x64 tiles, BK=64, dbuf, 48 KB LDS (3 blk/CU) ---
// FIN=0: 768 blocks/8 tb: u<32 -> q (orient1); u>=32 -> k or v (orient2).
// FIN=1: 256 blocks: final branch + residual, f32 out.
template <int FIN>
__global__ __launch_bounds__(256, 3) void conv_kernel(
    const unsigned short* __restrict__ whl,
    const unsigned short* __restrict__ actT,
    const float* __restrict__ bninv, const float* __restrict__ bnsh,
    unsigned short* __restrict__ dq, unsigned short* __restrict__ dk,
    unsigned short* __restrict__ dv, const float* __restrict__ tmp,
    float* __restrict__ outf) {
    __shared__ short At[2][128 * 64];
    __shared__ short Bt[2][64 * 64];
    int bz = blockIdx.x;
    int tb = bz & 7, u = bz >> 3;  // tb == XCD
    int br, m0, n0;
    bool isQ = false;
    if (FIN) {
        br = 3; m0 = (u >> 2) * 128; n0 = (u & 3) * 64;
    } else if (u < 32) {
        isQ = true; br = 0; m0 = (u >> 4) * 128; n0 = (u & 15) * 64;
    } else {
        int v = u - 32;
        br = 1 + (v >> 5); v &= 31;
        m0 = (v >> 2) * 128; n0 = (v & 3) * 64;
    }
    const int tid = threadIdx.x, lane = tid & 63, wid = tid >> 6;
    const int wm = wid >> 1, wn = wid & 1;
    const int l15 = lane & 15, l4 = lane >> 4;
    const unsigned short* wbase = whl + (size_t)br * 131072;
    const unsigned short* abase = actT + (size_t)tb * CN;
    f32x4 z = {0.f, 0.f, 0.f, 0.f};

    // A-tile: 128 rows x 64k. q: rows = c_out (whl). else: rows = n (act).
    // B-tile: 64 rows x 64k.  q: rows = n (act).     else: rows = c_out (whl).
    const unsigned short* pa[4];
    const unsigned short* pb[2];
#pragma unroll
    for (int c = 0; c < 4; ++c) {
        int s = c * 256 + tid, row = s >> 3, gsw = ((s & 7) ^ (row & 7)) * 8;
        pa[c] = isQ ? wbase + (size_t)(m0 + row) * 512 + gsw
                    : abase + (size_t)(m0 + row) * 256 + gsw;
    }
#pragma unroll
    for (int c = 0; c < 2; ++c) {
        int s = c * 256 + tid, row = s >> 3, gsw = ((s & 7) ^ (row & 7)) * 8;
        pb[c] = isQ ? abase + (size_t)(n0 + row) * 256 + gsw
                    : wbase + (size_t)(n0 + row) * 512 + gsw;
    }

    f32x4 acc[4][2];
#pragma unroll
    for (int i = 0; i < 4; ++i) { acc[i][0] = z; acc[i][1] = z; }

    auto stage = [&](int buf, int kt) {
        int kw = kt * 64, ka = (kt & 3) * 64;
        int offA = isQ ? kw : ka;
        int offB = isQ ? ka : kw;
#pragma unroll
        for (int c = 0; c < 4; ++c)
            async16(&At[buf][(c * 256 + tid) * 8], pa[c] + offA);
#pragma unroll
        for (int c = 0; c < 2; ++c)
            async16(&Bt[buf][(c * 256 + tid) * 8], pb[c] + offB);
    };

    stage(0, 0);
    __syncthreads();
    int cur = 0;
    for (int kt = 0; kt < 8; ++kt) {
        if (kt < 7) stage(cur ^ 1, kt + 1);
#pragma unroll
        for (int kk = 0; kk < 2; ++kk) {
            short8 af[4], bf[2];
#pragma unroll
            for (int f = 0; f < 4; ++f) {
                int rowa = wm * 64 + f * 16 + l15;
                int ka = ((kk * 4 + l4) ^ (rowa & 7)) << 4;
                af[f] = *(const short8*)((const char*)&At[cur][0] + rowa * 128 + ka);
            }
#pragma unroll
            for (int f = 0; f < 2; ++f) {
                int rowb = wn * 32 + f * 16 + l15;
                int kb2 = ((kk * 4 + l4) ^ (rowb & 7)) << 4;
                bf[f] = *(const short8*)((const char*)&Bt[cur][0] + rowb * 128 + kb2);
            }
#pragma unroll
            for (int i = 0; i < 4; ++i) {
                acc[i][0] = mfma16(af[i], bf[0], acc[i][0]);
                acc[i][1] = mfma16(af[i], bf[1], acc[i][1]);
            }
        }
        __syncthreads();
        cur ^= 1;
    }

    if (isQ) {
        // out n-major bf16 spiked (q)
#pragma unroll
        for (int i = 0; i < 4; ++i) {
            int cb4 = m0 + wm * 64 + i * 16 + l4 * 4;
            float4 inv = *(const float4*)&bninv[cb4];
            float4 sh = *(const float4*)&bnsh[cb4];
#pragma unroll
            for (int j = 0; j < 2; ++j) {
                int n = n0 + wn * 32 + j * 16 + l15;
                f32x4 a = acc[i][j];
                ushort4 u4;
                u4.x = bfbits(mspike(a[0] * inv.x + sh.x));
                u4.y = bfbits(mspike(a[1] * inv.y + sh.y));
                u4.z = bfbits(mspike(a[2] * inv.z + sh.z));
                u4.w = bfbits(mspike(a[3] * inv.w + sh.w));
                *(ushort4*)&dq[(size_t)tb * CN + (size_t)n * C_DIM + cb4] = u4;
            }
        }
    } else {
#pragma unroll
        for (int j = 0; j < 2; ++j) {
            int c = n0 + wn * 32 + j * 16 + l15;
            float inv = bninv[br * 256 + c];
            float sh = bnsh[br * 256 + c];
#pragma unroll
            for (int i = 0; i < 4; ++i) {
                int nb4 = m0 + wm * 64 + i * 16 + l4 * 4;
                f32x4 a = acc[i][j];
                size_t off = (size_t)tb * CN + (size_t)c * N_DIM + nb4;
                if (!FIN) {
                    ushort4 u4;
                    u4.x = bfbits(mspike(a[0] * inv + sh));
                    u4.y = bfbits(mspike(a[1] * inv + sh));
                    u4.z = bfbits(mspike(a[2] * inv + sh));
                    u4.w = bfbits(mspike(a[3] * inv + sh));
                    unsigned short* dst = (br == 1) ? dk : dv;
                    *(ushort4*)&dst[off] = u4;
                } else {
                    float4 t4 = *(const float4*)&tmp[off];
                    float4 o;
                    o.x = a[0] * inv + sh + t4.x;
                    o.y = a[1] * inv + sh + t4.y;
                    o.z = a[2] * inv + sh + t4.z;
                    o.w = a[3] * inv + sh + t4.w;
                    *(float4*)&outf[off] = o;
                }
            }
        }
    }
}

// ---- attention (256 blocks): kTv exact + hi/lo split + PV -----------------
__global__ __launch_bounds__(256) void attn_kernel(
    const unsigned short* __restrict__ skD, const unsigned short* __restrict__ svD,
    const unsigned short* __restrict__ sqT, unsigned short* __restrict__ soT) {
    __shared__ float pbuf[4][32][33];
    __shared__ unsigned short aop[64][36];  // pad 32->36: 8-way -> 4-way bank
    int tb = blockIdx.x & 7, u = blockIdx.x >> 3;
    int h = u >> 2, nc = u & 3;
    int tid = threadIdx.x, lane = tid & 63, w = tid >> 6;
    int l15 = lane & 15, l4 = lane >> 4;
    const unsigned short* kb = skD + (size_t)tb * CN + (size_t)h * 32 * N_DIM;
    const unsigned short* vb = svD + (size_t)tb * CN + (size_t)h * 32 * N_DIM;
    f32x4 z = {0.f, 0.f, 0.f, 0.f};

    f32x4 acc[2][2];
    acc[0][0] = z; acc[0][1] = z; acc[1][0] = z; acc[1][1] = z;
    for (int ks = 0; ks < 8; ++ks) {
        int n0 = w * 256 + ks * 32 + l4 * 8;
        short8 a0 = *(const short8*)&kb[(size_t)l15 * N_DIM + n0];
        short8 a1 = *(const short8*)&kb[(size_t)(16 + l15) * N_DIM + n0];
        short8 b0 = *(const short8*)&vb[(size_t)l15 * N_DIM + n0];
        short8 b1 = *(const short8*)&vb[(size_t)(16 + l15) * N_DIM + n0];
        acc[0][0] = mfma16(a0, b0, acc[0][0]);
        acc[0][1] = mfma16(a0, b1, acc[0][1]);
        acc[1][0] = mfma16(a1, b0, acc[1][0]);
        acc[1][1] = mfma16(a1, b1, acc[1][1]);
    }
#pragma unroll
    for (int i = 0; i < 2; ++i)
#pragma unroll
        for (int j = 0; j < 2; ++j)
#pragma unroll
            for (int r = 0; r < 4; ++r)
                pbuf[w][i * 16 + l4 * 4 + r][j * 16 + l15] = acc[i][j][r];
    __syncthreads();
    {
        int d1 = tid >> 3, d2 = (tid & 7) * 4;
        float4 s = make_float4(0.f, 0.f, 0.f, 0.f);
#pragma unroll
        for (int ww = 0; ww < 4; ++ww) {
            float4 p = *(const float4*)&pbuf[ww][d1][d2];
            s.x += p.x; s.y += p.y; s.z += p.z; s.w += p.w;
        }
        float xs[4] = {s.x, s.y, s.z, s.w};
#pragma unroll
        for (int q4 = 0; q4 < 4; ++q4) {
            __hip_bfloat16 hh = __float2bfloat16(xs[q4]);
            float hf = __bfloat162float(hh);
            __hip_bfloat16 ll = __float2bfloat16(xs[q4] - hf);
            aop[d1][d2 + q4] = *(unsigned short*)&hh;
            aop[32 + d1][d2 + q4] = *(unsigned short*)&ll;
        }
    }
    __syncthreads();
    short8 afr[2][2];
#pragma unroll
    for (int kk = 0; kk < 2; ++kk)
#pragma unroll
        for (int fm = 0; fm < 2; ++fm) {
            short8 v;
#pragma unroll
            for (int i = 0; i < 8; ++i)
                v[i] = (short)aop[kk * 32 + l4 * 8 + i][fm * 16 + l15];
            afr[kk][fm] = v;
        }
    const unsigned short* qb = sqT + (size_t)tb * CN;
    unsigned short* ob = soT + (size_t)tb * CN;
#pragma unroll
    for (int fn = 0; fn < 4; ++fn) {
        int n = nc * 256 + w * 64 + fn * 16 + l15;
        short8 bq = *(const short8*)&qb[(size_t)n * C_DIM + h * 32 + l4 * 8];
        f32x4 o0 = z, o1 = z;
        o0 = mfma16(afr[0][0], bq, o0);
        o0 = mfma16(afr[1][0], bq, o0);
        o1 = mfma16(afr[0][1], bq, o1);
        o1 = mfma16(afr[1][1], bq, o1);
        ushort4 u0, u1;
        u0.x = bfbits(mspike(SCALE * o0[0]));
        u0.y = bfbits(mspike(SCALE * o0[1]));
        u0.z = bfbits(mspike(SCALE * o0[2]));
        u0.w = bfbits(mspike(SCALE * o0[3]));
        u1.x = bfbits(mspike(SCALE * o1[0]));
        u1.y = bfbits(mspike(SCALE * o1[1]));
        u1.z = bfbits(mspike(SCALE * o1[2]));
        u1.w = bfbits(mspike(SCALE * o1[3]));
        size_t obase = (size_t)n * C_DIM + h * 32 + l4 * 4;
        *(ushort4*)&ob[obase] = u0;
        *(ushort4*)&ob[obase + 16] = u1;
    }
}

extern "C" void kernel_launch(void* const* d_in, const int* in_sizes, int n_in,
                              void* d_out, int out_size, void* d_ws, size_t ws_size,
                              hipStream_t stream) {
    const float* query = (const float*)d_in[0];
    const float* qpos  = (const float*)d_in[3];
    const float* convw = (const float*)d_in[4];
    const float* convb = (const float*)d_in[5];
    const float* gam   = (const float*)d_in[6];
    const float* bet   = (const float*)d_in[7];
    const float* mn    = (const float*)d_in[8];
    const float* vr    = (const float*)d_in[9];
    float* out = (float*)d_out;

    char* ws = (char*)d_ws;
    float* tmp = (float*)ws;
    unsigned short* sxT = (unsigned short*)(ws + (size_t)TOT * 4);
    unsigned short* sqT = sxT + TOT;
    unsigned short* skD = sqT + TOT;
    unsigned short* svD = skD + TOT;
    unsigned short* soT = svD + TOT;
    unsigned short* whl = soT + TOT;
    float* bninv = (float*)(whl + 4 * 256 * 512);
    float* bnsh = bninv + 1024;

    prep_spike_kernel<<<512, 256, 0, stream>>>(
        query, qpos, convw, convb, gam, bet, mn, vr, tmp, sxT, whl, bninv, bnsh);
    conv_kernel<0><<<768, 256, 0, stream>>>(
        whl, sxT, bninv, bnsh, sqT, skD, svD, nullptr, nullptr);
    attn_kernel<<<256, 256, 0, stream>>>(skD, svD, sqT, soT);
    conv_kernel<1><<<256, 256, 0, stream>>>(
        whl, soT, bninv, bnsh, nullptr, nullptr, nullptr, tmp, out);
}

// Round 8
// 42.225 us; speedup vs baseline: 9.8269x; 1.0335x over previous
//
#include <hip/hip_runtime.h>
#include <hip/hip_bf16.h>
#include <math.h>

#define N_DIM 1024
#define C_DIM 256
#define CN (C_DIM * N_DIM)
#define TOT (8 * CN)
#define BN_EPS 1e-5f
#define SCALE 0.1f

typedef short short8 __attribute__((ext_vector_type(8)));
typedef float f32x4 __attribute__((ext_vector_type(4)));

__device__ __forceinline__ float mspike(float x) {
    return rintf(fminf(fmaxf(x, 0.f), 4.f)) * 0.25f;
}
__device__ __forceinline__ unsigned short bfbits(float x) {
    __hip_bfloat16 h = __float2bfloat16(x);
    return *reinterpret_cast<unsigned short*>(&h);
}
__device__ __forceinline__ f32x4 mfma16(short8 a, short8 b, f32x4 c) {
    return __builtin_amdgcn_mfma_f32_16x16x32_bf16(a, b, c, 0, 0, 0);
}
__device__ __forceinline__ void async16(void* lds, const void* g) {
    __builtin_amdgcn_global_load_lds(
        (const __attribute__((address_space(1))) void*)g,
        (__attribute__((address_space(3))) void*)lds, 16, 0, 0);
}

// ---- L1 (512 blocks): add+spike+transpose + 2 weight rows per block -------
__global__ __launch_bounds__(256) void prep_spike_kernel(
    const float* __restrict__ q, const float* __restrict__ qp,
    const float* __restrict__ w, const float* __restrict__ cb,
    const float* __restrict__ g, const float* __restrict__ bet,
    const float* __restrict__ mn, const float* __restrict__ vr,
    float* __restrict__ tmp, unsigned short* __restrict__ sxT,
    unsigned short* __restrict__ whl, float* __restrict__ bninv,
    float* __restrict__ bnsh) {
    int logical = ((blockIdx.x & 7) << 6) + (blockIdx.x >> 3);
    int t = threadIdx.x;
    __shared__ float ld[64][65];
    {
        int tb = logical >> 6, u = logical & 63;
        int c0 = (u >> 4) * 64, n0 = (u & 15) * 64;
        int cl = t >> 4, nl = (t & 15) * 4;
        size_t base = (size_t)tb * CN;
#pragma unroll
        for (int r = 0; r < 4; ++r) {
            int c = cl + r * 16;
            size_t off = base + (size_t)(c0 + c) * N_DIM + n0 + nl;
            float4 a = *(const float4*)&q[off];
            float4 b = *(const float4*)&qp[off];
            float4 s = make_float4(a.x + b.x, a.y + b.y, a.z + b.z, a.w + b.w);
            *(float4*)&tmp[off] = s;
            ld[c][nl] = mspike(s.x); ld[c][nl + 1] = mspike(s.y);
            ld[c][nl + 2] = mspike(s.z); ld[c][nl + 3] = mspike(s.w);
        }
        __syncthreads();
        int nl2 = t >> 2, cg2 = (t & 3) * 16;
        size_t ob = base + (size_t)(n0 + nl2) * C_DIM + c0 + cg2;
        short8 v0, v1;
#pragma unroll
        for (int j = 0; j < 8; ++j) {
            v0[j] = (short)bfbits(ld[cg2 + j][nl2]);
            v1[j] = (short)bfbits(ld[cg2 + 8 + j][nl2]);
        }
        *(short8*)&sxT[ob] = v0;
        *(short8*)&sxT[ob + 8] = v1;
    }
    {
        int row = 2 * logical + (t >> 7);
        int tl = t & 127;
        float2 wv = *(const float2*)&w[(size_t)row * 256 + tl * 2];
        __hip_bfloat16 h0 = __float2bfloat16(wv.x);
        __hip_bfloat16 h1 = __float2bfloat16(wv.y);
        __hip_bfloat16 l0 = __float2bfloat16(wv.x - __bfloat162float(h0));
        __hip_bfloat16 l1 = __float2bfloat16(wv.y - __bfloat162float(h1));
        size_t base = (size_t)row * 512;
        *(ushort2*)&whl[base + tl * 2] =
            make_ushort2(*(unsigned short*)&h0, *(unsigned short*)&h1);
        *(ushort2*)&whl[base + 256 + tl * 2] =
            make_ushort2(*(unsigned short*)&l0, *(unsigned short*)&l1);
        if (tl == 0) {
            float inv = g[row] / sqrtf(vr[row] + BN_EPS);
            bninv[row] = inv;
            bnsh[row] = (cb[row] - mn[row]) * inv + bet[row];
        }
    }
}

// ---- conv GEMM, 128x64 out-tile, panel-reuse staging, 64 KB LDS ----------
// FIN=0 (768 blocks): u<32 q (A=Whl full K=512, B=act panels reused);
//                     u>=32 k/v (A=act panels, B=Whi+Wlo share the panel).
// FIN=1 (256 blocks): final conv, W_lo DROPPED (K=256), + residual, f32 out.
template <int FIN>
__global__ __launch_bounds__(256, 2) void conv_kernel(
    const unsigned short* __restrict__ whl,
    const unsigned short* __restrict__ actT,
    const float* __restrict__ bninv, const float* __restrict__ bnsh,
    unsigned short* __restrict__ dq, unsigned short* __restrict__ dk,
    unsigned short* __restrict__ dv, const float* __restrict__ tmp,
    float* __restrict__ outf) {
    __shared__ short At[2][128 * 64];     // 32 KB
    __shared__ short Bt[2][2][64 * 64];   // 32 KB (q-mode: 4 panels of 8 KB)
    int bz = blockIdx.x;
    int tb = bz & 7, u = bz >> 3;  // tb == XCD
    int br, m0, n0;
    bool isQ = false;
    if (FIN) {
        br = 3; m0 = (u >> 2) * 128; n0 = (u & 3) * 64;
    } else if (u < 32) {
        isQ = true; br = 0; m0 = (u >> 4) * 128; n0 = (u & 15) * 64;
    } else {
        int v = u - 32;
        br = 1 + (v >> 5); v &= 31;
        m0 = (v >> 2) * 128; n0 = (v & 3) * 64;
    }
    const int tid = threadIdx.x, lane = tid & 63, wid = tid >> 6;
    const int wm = wid >> 1, wn = wid & 1;
    const int l15 = lane & 15, l4 = lane >> 4;
    const unsigned short* wbase = whl + (size_t)br * 131072;
    const unsigned short* abase = actT + (size_t)tb * CN;
    f32x4 z = {0.f, 0.f, 0.f, 0.f};
    f32x4 acc[4][2];
#pragma unroll
    for (int i = 0; i < 4; ++i) { acc[i][0] = z; acc[i][1] = z; }

    if (!FIN && isQ) {
        // ---- q: A = Whl rows c_out (K=512, 8 kt), B = act panels (reused) --
        const unsigned short* pa[4];
        const unsigned short* pb[2];
#pragma unroll
        for (int c = 0; c < 4; ++c) {
            int s = c * 256 + tid, row = s >> 3, gsw = ((s & 7) ^ (row & 7)) * 8;
            pa[c] = wbase + (size_t)(m0 + row) * 512 + gsw;
        }
#pragma unroll
        for (int c = 0; c < 2; ++c) {
            int s = c * 256 + tid, row = s >> 3, gsw = ((s & 7) ^ (row & 7)) * 8;
            pb[c] = abase + (size_t)(n0 + row) * 256 + gsw;
        }
        short* bflat = (short*)Bt;
        auto stageA = [&](int buf, int kt) {
#pragma unroll
            for (int c = 0; c < 4; ++c)
                async16(&At[buf][(c * 256 + tid) * 8], pa[c] + kt * 64);
        };
        auto stageB = [&](int p) {
#pragma unroll
            for (int c = 0; c < 2; ++c)
                async16(&bflat[p * 4096 + (c * 256 + tid) * 8], pb[c] + p * 64);
        };
        stageA(0, 0);
        stageB(0);
        __syncthreads();
        int cur = 0;
        for (int kt = 0; kt < 8; ++kt) {
            if (kt < 7) stageA(cur ^ 1, kt + 1);
            if (kt < 3) stageB(kt + 1);
            const char* bbase = (const char*)bflat + (kt & 3) * 8192;
#pragma unroll
            for (int kk = 0; kk < 2; ++kk) {
                short8 af[4], bf[2];
#pragma unroll
                for (int f = 0; f < 4; ++f) {
                    int rowa = wm * 64 + f * 16 + l15;
                    int ka = ((kk * 4 + l4) ^ (rowa & 7)) << 4;
                    af[f] = *(const short8*)((const char*)&At[cur][0] + rowa * 128 + ka);
                }
#pragma unroll
                for (int f = 0; f < 2; ++f) {
                    int rowb = wn * 32 + f * 16 + l15;
                    int kb2 = ((kk * 4 + l4) ^ (rowb & 7)) << 4;
                    bf[f] = *(const short8*)(bbase + rowb * 128 + kb2);
                }
#pragma unroll
                for (int i = 0; i < 4; ++i) {
                    acc[i][0] = mfma16(af[i], bf[0], acc[i][0]);
                    acc[i][1] = mfma16(af[i], bf[1], acc[i][1]);
                }
            }
            __syncthreads();
            cur ^= 1;
        }
#pragma unroll
        for (int i = 0; i < 4; ++i) {
            int cb4 = m0 + wm * 64 + i * 16 + l4 * 4;
            float4 inv = *(const float4*)&bninv[cb4];
            float4 sh = *(const float4*)&bnsh[cb4];
#pragma unroll
            for (int j = 0; j < 2; ++j) {
                int n = n0 + wn * 32 + j * 16 + l15;
                f32x4 a = acc[i][j];
                ushort4 u4;
                u4.x = bfbits(mspike(a[0] * inv.x + sh.x));
                u4.y = bfbits(mspike(a[1] * inv.y + sh.y));
                u4.z = bfbits(mspike(a[2] * inv.z + sh.z));
                u4.w = bfbits(mspike(a[3] * inv.w + sh.w));
                *(ushort4*)&dq[(size_t)tb * CN + (size_t)n * C_DIM + cb4] = u4;
            }
        }
    } else {
        // ---- k/v/fin: A = act panels (K=256, 4 outer), B = Whi [+ Wlo] ----
        const unsigned short* pa[4];
        const unsigned short* pbh[2];
        const unsigned short* pbl[2];
#pragma unroll
        for (int c = 0; c < 4; ++c) {
            int s = c * 256 + tid, row = s >> 3, gsw = ((s & 7) ^ (row & 7)) * 8;
            pa[c] = abase + (size_t)(m0 + row) * 256 + gsw;
        }
#pragma unroll
        for (int c = 0; c < 2; ++c) {
            int s = c * 256 + tid, row = s >> 3, gsw = ((s & 7) ^ (row & 7)) * 8;
            pbh[c] = wbase + (size_t)(n0 + row) * 512 + gsw;
            pbl[c] = pbh[c] + 256;
        }
        auto stage = [&](int buf, int p) {
#pragma unroll
            for (int c = 0; c < 4; ++c)
                async16(&At[buf][(c * 256 + tid) * 8], pa[c] + p * 64);
#pragma unroll
            for (int c = 0; c < 2; ++c)
                async16(&Bt[buf][0][(c * 256 + tid) * 8], pbh[c] + p * 64);
            if (!FIN) {
#pragma unroll
                for (int c = 0; c < 2; ++c)
                    async16(&Bt[buf][1][(c * 256 + tid) * 8], pbl[c] + p * 64);
            }
        };
        stage(0, 0);
        __syncthreads();
        int cur = 0;
        for (int p = 0; p < 4; ++p) {
            if (p < 3) stage(cur ^ 1, p + 1);
#pragma unroll
            for (int kk = 0; kk < 2; ++kk) {
                short8 af[4];
#pragma unroll
                for (int f = 0; f < 4; ++f) {
                    int rowa = wm * 64 + f * 16 + l15;
                    int ka = ((kk * 4 + l4) ^ (rowa & 7)) << 4;
                    af[f] = *(const short8*)((const char*)&At[cur][0] + rowa * 128 + ka);
                }
                short8 bfh[2], bfl[2];
#pragma unroll
                for (int f = 0; f < 2; ++f) {
                    int rowb = wn * 32 + f * 16 + l15;
                    int kb2 = ((kk * 4 + l4) ^ (rowb & 7)) << 4;
                    bfh[f] = *(const short8*)((const char*)&Bt[cur][0][0] + rowb * 128 + kb2);
                    if (!FIN)
                        bfl[f] = *(const short8*)((const char*)&Bt[cur][1][0] + rowb * 128 + kb2);
                }
#pragma unroll
                for (int i = 0; i < 4; ++i) {
                    acc[i][0] = mfma16(af[i], bfh[0], acc[i][0]);
                    acc[i][1] = mfma16(af[i], bfh[1], acc[i][1]);
                }
                if (!FIN) {
#pragma unroll
                    for (int i = 0; i < 4; ++i) {
                        acc[i][0] = mfma16(af[i], bfl[0], acc[i][0]);
                        acc[i][1] = mfma16(af[i], bfl[1], acc[i][1]);
                    }
                }
            }
            __syncthreads();
            cur ^= 1;
        }
#pragma unroll
        for (int j = 0; j < 2; ++j) {
            int c = n0 + wn * 32 + j * 16 + l15;
            float inv = bninv[br * 256 + c];
            float sh = bnsh[br * 256 + c];
#pragma unroll
            for (int i = 0; i < 4; ++i) {
                int nb4 = m0 + wm * 64 + i * 16 + l4 * 4;
                f32x4 a = acc[i][j];
                size_t off = (size_t)tb * CN + (size_t)c * N_DIM + nb4;
                if (!FIN) {
                    ushort4 u4;
                    u4.x = bfbits(mspike(a[0] * inv + sh));
                    u4.y = bfbits(mspike(a[1] * inv + sh));
                    u4.z = bfbits(mspike(a[2] * inv + sh));
                    u4.w = bfbits(mspike(a[3] * inv + sh));
                    unsigned short* dst = (br == 1) ? dk : dv;
                    *(ushort4*)&dst[off] = u4;
                } else {
                    float4 t4 = *(const float4*)&tmp[off];
                    float4 o;
                    o.x = a[0] * inv + sh + t4.x;
                    o.y = a[1] * inv + sh + t4.y;
                    o.z = a[2] * inv + sh + t4.z;
                    o.w = a[3] * inv + sh + t4.w;
                    *(float4*)&outf[off] = o;
                }
            }
        }
    }
}

// ---- attention (256 blocks): kTv exact + hi/lo split + PV -----------------
__global__ __launch_bounds__(256) void attn_kernel(
    const unsigned short* __restrict__ skD, const unsigned short* __restrict__ svD,
    const unsigned short* __restrict__ sqT, unsigned short* __restrict__ soT) {
    __shared__ float pbuf[4][32][33];
    __shared__ unsigned short aop[64][36];
    int tb = blockIdx.x & 7, u = blockIdx.x >> 3;
    int h = u >> 2, nc = u & 3;
    int tid = threadIdx.x, lane = tid & 63, w = tid >> 6;
    int l15 = lane & 15, l4 = lane >> 4;
    const unsigned short* kb = skD + (size_t)tb * CN + (size_t)h * 32 * N_DIM;
    const unsigned short* vb = svD + (size_t)tb * CN + (size_t)h * 32 * N_DIM;
    f32x4 z = {0.f, 0.f, 0.f, 0.f};

    f32x4 acc[2][2];
    acc[0][0] = z; acc[0][1] = z; acc[1][0] = z; acc[1][1] = z;
    for (int ks = 0; ks < 8; ++ks) {
        int n0 = w * 256 + ks * 32 + l4 * 8;
        short8 a0 = *(const short8*)&kb[(size_t)l15 * N_DIM + n0];
        short8 a1 = *(const short8*)&kb[(size_t)(16 + l15) * N_DIM + n0];
        short8 b0 = *(const short8*)&vb[(size_t)l15 * N_DIM + n0];
        short8 b1 = *(const short8*)&vb[(size_t)(16 + l15) * N_DIM + n0];
        acc[0][0] = mfma16(a0, b0, acc[0][0]);
        acc[0][1] = mfma16(a0, b1, acc[0][1]);
        acc[1][0] = mfma16(a1, b0, acc[1][0]);
        acc[1][1] = mfma16(a1, b1, acc[1][1]);
    }
#pragma unroll
    for (int i = 0; i < 2; ++i)
#pragma unroll
        for (int j = 0; j < 2; ++j)
#pragma unroll
            for (int r = 0; r < 4; ++r)
                pbuf[w][i * 16 + l4 * 4 + r][j * 16 + l15] = acc[i][j][r];
    __syncthreads();
    {
        int d1 = tid >> 3, d2 = (tid & 7) * 4;
        float4 s = make_float4(0.f, 0.f, 0.f, 0.f);
#pragma unroll
        for (int ww = 0; ww < 4; ++ww) {
            float4 p = *(const float4*)&pbuf[ww][d1][d2];
            s.x += p.x; s.y += p.y; s.z += p.z; s.w += p.w;
        }
        float xs[4] = {s.x, s.y, s.z, s.w};
#pragma unroll
        for (int q4 = 0; q4 < 4; ++q4) {
            __hip_bfloat16 hh = __float2bfloat16(xs[q4]);
            float hf = __bfloat162float(hh);
            __hip_bfloat16 ll = __float2bfloat16(xs[q4] - hf);
            aop[d1][d2 + q4] = *(unsigned short*)&hh;
            aop[32 + d1][d2 + q4] = *(unsigned short*)&ll;
        }
    }
    __syncthreads();
    short8 afr[2][2];
#pragma unroll
    for (int kk = 0; kk < 2; ++kk)
#pragma unroll
        for (int fm = 0; fm < 2; ++fm) {
            short8 v;
#pragma unroll
            for (int i = 0; i < 8; ++i)
                v[i] = (short)aop[kk * 32 + l4 * 8 + i][fm * 16 + l15];
            afr[kk][fm] = v;
        }
    const unsigned short* qb = sqT + (size_t)tb * CN;
    unsigned short* ob = soT + (size_t)tb * CN;
#pragma unroll
    for (int fn = 0; fn < 4; ++fn) {
        int n = nc * 256 + w * 64 + fn * 16 + l15;
        short8 bq = *(const short8*)&qb[(size_t)n * C_DIM + h * 32 + l4 * 8];
        f32x4 o0 = z, o1 = z;
        o0 = mfma16(afr[0][0], bq, o0);
        o0 = mfma16(afr[1][0], bq, o0);
        o1 = mfma16(afr[0][1], bq, o1);
        o1 = mfma16(afr[1][1], bq, o1);
        ushort4 u0, u1;
        u0.x = bfbits(mspike(SCALE * o0[0]));
        u0.y = bfbits(mspike(SCALE * o0[1]));
        u0.z = bfbits(mspike(SCALE * o0[2]));
        u0.w = bfbits(mspike(SCALE * o0[3]));
        u1.x = bfbits(mspike(SCALE * o1[0]));
        u1.y = bfbits(mspike(SCALE * o1[1]));
        u1.z = bfbits(mspike(SCALE * o1[2]));
        u1.w = bfbits(mspike(SCALE * o1[3]));
        size_t obase = (size_t)n * C_DIM + h * 32 + l4 * 4;
        *(ushort4*)&ob[obase] = u0;
        *(ushort4*)&ob[obase + 16] = u1;
    }
}

extern "C" void kernel_launch(void* const* d_in, const int* in_sizes, int n_in,
                              void* d_out, int out_size, void* d_ws, size_t ws_size,
                              hipStream_t stream) {
    const float* query = (const float*)d_in[0];
    const float* qpos  = (const float*)d_in[3];
    const float* convw = (const float*)d_in[4];
    const float* convb = (const float*)d_in[5];
    const float* gam   = (const float*)d_in[6];
    const float* bet   = (const float*)d_in[7];
    const float* mn    = (const float*)d_in[8];
    const float* vr    = (const float*)d_in[9];
    float* out = (float*)d_out;

    char* ws = (char*)d_ws;
    float* tmp = (float*)ws;
    unsigned short* sxT = (unsigned short*)(ws + (size_t)TOT * 4);
    unsigned short* sqT = sxT + TOT;
    unsigned short* skD = sqT + TOT;
    unsigned short* svD = skD + TOT;
    unsigned short* soT = svD + TOT;
    unsigned short* whl = soT + TOT;
    float* bninv = (float*)(whl + 4 * 256 * 512);
    float* bnsh = bninv + 1024;

    prep_spike_kernel<<<512, 256, 0, stream>>>(
        query, qpos, convw, convb, gam, bet, mn, vr, tmp, sxT, whl, bninv, bnsh);
    conv_kernel<0><<<768, 256, 0, stream>>>(
        whl, sxT, bninv, bnsh, sqT, skD, svD, nullptr, nullptr);
    attn_kernel<<<256, 256, 0, stream>>>(skD, svD, sqT, soT);
    conv_kernel<1><<<256, 256, 0, stream>>>(
        whl, soT, bninv, bnsh, nullptr, nullptr, nullptr, tmp, out);
}

// Round 9
// 34.179 us; speedup vs baseline: 12.1401x; 1.2354x over previous
//
#include <hip/hip_runtime.h>
#include <hip/hip_bf16.h>
#include <math.h>

#define N_DIM 1024
#define C_DIM 256
#define CN (C_DIM * N_DIM)
#define TOT (8 * CN)
#define BN_EPS 1e-5f
#define SCALE 0.1f

typedef short short8 __attribute__((ext_vector_type(8)));
typedef float f32x4 __attribute__((ext_vector_type(4)));
typedef _Float16 half8 __attribute__((ext_vector_type(8)));

__device__ __forceinline__ float mspike(float x) {
    return rintf(fminf(fmaxf(x, 0.f), 4.f)) * 0.25f;
}
__device__ __forceinline__ unsigned short bfbits(float x) {
    __hip_bfloat16 h = __float2bfloat16(x);
    return *reinterpret_cast<unsigned short*>(&h);
}
__device__ __forceinline__ f32x4 mfma16(short8 a, short8 b, f32x4 c) {
    return __builtin_amdgcn_mfma_f32_16x16x32_bf16(a, b, c, 0, 0, 0);
}
__device__ __forceinline__ void async16(void* lds, const void* g) {
    __builtin_amdgcn_global_load_lds(
        (const __attribute__((address_space(1))) void*)g,
        (__attribute__((address_space(3))) void*)lds, 16, 0, 0);
}

// ==== K1 (512 blocks): add+spike+transpose + 2 weight rows per block =======
__global__ __launch_bounds__(256) void prep_spike_kernel(
    const float* __restrict__ q, const float* __restrict__ qp,
    const float* __restrict__ w, const float* __restrict__ cb,
    const float* __restrict__ g, const float* __restrict__ bet,
    const float* __restrict__ mn, const float* __restrict__ vr,
    float* __restrict__ tmp, unsigned short* __restrict__ sxT,
    unsigned short* __restrict__ whl, float* __restrict__ bninv,
    float* __restrict__ bnsh) {
    int logical = ((blockIdx.x & 7) << 6) + (blockIdx.x >> 3);
    int t = threadIdx.x;
    __shared__ float ld[64][65];
    {
        int tb = logical >> 6, u = logical & 63;
        int c0 = (u >> 4) * 64, n0 = (u & 15) * 64;
        int cl = t >> 4, nl = (t & 15) * 4;
        size_t base = (size_t)tb * CN;
#pragma unroll
        for (int r = 0; r < 4; ++r) {
            int c = cl + r * 16;
            size_t off = base + (size_t)(c0 + c) * N_DIM + n0 + nl;
            float4 a = *(const float4*)&q[off];
            float4 b = *(const float4*)&qp[off];
            float4 s = make_float4(a.x + b.x, a.y + b.y, a.z + b.z, a.w + b.w);
            *(float4*)&tmp[off] = s;
            ld[c][nl] = mspike(s.x); ld[c][nl + 1] = mspike(s.y);
            ld[c][nl + 2] = mspike(s.z); ld[c][nl + 3] = mspike(s.w);
        }
        __syncthreads();
        int nl2 = t >> 2, cg2 = (t & 3) * 16;
        size_t ob = base + (size_t)(n0 + nl2) * C_DIM + c0 + cg2;
        short8 v0, v1;
#pragma unroll
        for (int j = 0; j < 8; ++j) {
            v0[j] = (short)bfbits(ld[cg2 + j][nl2]);
            v1[j] = (short)bfbits(ld[cg2 + 8 + j][nl2]);
        }
        *(short8*)&sxT[ob] = v0;
        *(short8*)&sxT[ob + 8] = v1;
    }
    {
        int row = 2 * logical + (t >> 7);
        int tl = t & 127;
        float2 wv = *(const float2*)&w[(size_t)row * 256 + tl * 2];
        __hip_bfloat16 h0 = __float2bfloat16(wv.x);
        __hip_bfloat16 h1 = __float2bfloat16(wv.y);
        __hip_bfloat16 l0 = __float2bfloat16(wv.x - __bfloat162float(h0));
        __hip_bfloat16 l1 = __float2bfloat16(wv.y - __bfloat162float(h1));
        size_t base = (size_t)row * 512;
        *(ushort2*)&whl[base + tl * 2] =
            make_ushort2(*(unsigned short*)&h0, *(unsigned short*)&h1);
        *(ushort2*)&whl[base + 256 + tl * 2] =
            make_ushort2(*(unsigned short*)&l0, *(unsigned short*)&l1);
        if (tl == 0) {
            float inv = g[row] / sqrtf(vr[row] + BN_EPS);
            bninv[row] = inv;
            bnsh[row] = (cb[row] - mn[row]) * inv + bet[row];
        }
    }
}

// ==== K2 (512 blocks): q conv (u<32) | fused kv conv + partial kTv (u>=32) ==
// kv blocks write NO k/v to global; only part[slice][tb][h][d2][d1] f16.
__global__ __launch_bounds__(256, 2) void conv_qkv_kernel(
    const unsigned short* __restrict__ whl,
    const unsigned short* __restrict__ actT,
    const float* __restrict__ bninv, const float* __restrict__ bnsh,
    unsigned short* __restrict__ dq, _Float16* __restrict__ part) {
    __shared__ char lds[49152];
    int bz = blockIdx.x;
    int tb = bz & 7, u = bz >> 3;
    const int tid = threadIdx.x, lane = tid & 63, wid = tid >> 6;
    const int wm = wid >> 1, wn = wid & 1;
    const int l15 = lane & 15, l4 = lane >> 4;
    const unsigned short* abase = actT + (size_t)tb * CN;
    f32x4 z = {0.f, 0.f, 0.f, 0.f};

    if (u < 32) {
        // ---------------- q branch: A=W0hl (K=512), B=act panels resident ---
        int m0 = (u >> 4) * 128, n0 = (u & 15) * 64;
        short* Bp = (short*)lds;              // 4 panels x 4096 shorts (32 KB)
        short* Aq = (short*)(lds + 32768);    // 128x64 (16 KB)
        const unsigned short* pa[4];
        const unsigned short* pb[2];
#pragma unroll
        for (int c = 0; c < 4; ++c) {
            int s = c * 256 + tid, row = s >> 3, gsw = ((s & 7) ^ (row & 7)) * 8;
            pa[c] = whl + (size_t)(m0 + row) * 512 + gsw;
        }
#pragma unroll
        for (int c = 0; c < 2; ++c) {
            int s = c * 256 + tid, row = s >> 3, gsw = ((s & 7) ^ (row & 7)) * 8;
            pb[c] = abase + (size_t)(n0 + row) * 256 + gsw;
        }
        f32x4 acc[4][2];
#pragma unroll
        for (int i = 0; i < 4; ++i) { acc[i][0] = z; acc[i][1] = z; }
        // prologue: all 4 B panels + A(0)
#pragma unroll
        for (int p = 0; p < 4; ++p)
#pragma unroll
            for (int c = 0; c < 2; ++c)
                async16(&Bp[p * 4096 + (c * 256 + tid) * 8], pb[c] + p * 64);
#pragma unroll
        for (int c = 0; c < 4; ++c)
            async16(&Aq[(c * 256 + tid) * 8], pa[c]);
        __syncthreads();
        for (int kt = 0; kt < 8; ++kt) {
            const char* bbase = (const char*)(Bp + (kt & 3) * 4096);
#pragma unroll
            for (int kk = 0; kk < 2; ++kk) {
                short8 af[4], bf[2];
#pragma unroll
                for (int f = 0; f < 4; ++f) {
                    int rowa = wm * 64 + f * 16 + l15;
                    int ka = ((kk * 4 + l4) ^ (rowa & 7)) << 4;
                    af[f] = *(const short8*)((const char*)Aq + rowa * 128 + ka);
                }
#pragma unroll
                for (int f = 0; f < 2; ++f) {
                    int rowb = wn * 32 + f * 16 + l15;
                    int kb2 = ((kk * 4 + l4) ^ (rowb & 7)) << 4;
                    bf[f] = *(const short8*)(bbase + rowb * 128 + kb2);
                }
#pragma unroll
                for (int i = 0; i < 4; ++i) {
                    acc[i][0] = mfma16(af[i], bf[0], acc[i][0]);
                    acc[i][1] = mfma16(af[i], bf[1], acc[i][1]);
                }
            }
            __syncthreads();
            if (kt < 7) {
#pragma unroll
                for (int c = 0; c < 4; ++c)
                    async16(&Aq[(c * 256 + tid) * 8], pa[c] + (kt + 1) * 64);
                __syncthreads();
            }
        }
#pragma unroll
        for (int i = 0; i < 4; ++i) {
            int cb4 = m0 + wm * 64 + i * 16 + l4 * 4;
            float4 inv = *(const float4*)&bninv[cb4];
            float4 sh = *(const float4*)&bnsh[cb4];
#pragma unroll
            for (int j = 0; j < 2; ++j) {
                int n = n0 + wn * 32 + j * 16 + l15;
                f32x4 a = acc[i][j];
                ushort4 u4;
                u4.x = bfbits(mspike(a[0] * inv.x + sh.x));
                u4.y = bfbits(mspike(a[1] * inv.y + sh.y));
                u4.z = bfbits(mspike(a[2] * inv.z + sh.z));
                u4.w = bfbits(mspike(a[3] * inv.w + sh.w));
                *(ushort4*)&dq[(size_t)tb * CN + (size_t)n * C_DIM + cb4] = u4;
            }
        }
    } else {
        // -------- fused k+v: A=act (K=256), B=khi,klo,vhi,vlo; then kTv -----
        int v = u - 32;
        int m0 = (v >> 2) * 128, c0t = v & 3, n0 = c0t * 64;
        short* At = (short*)lds;                       // 16 KB
        char* Bb = lds + 16384;                        // 4 x 8 KB
        const unsigned short* pa[4];
        const unsigned short* pw[4][2];  // [khi,klo,vhi,vlo][c]
#pragma unroll
        for (int c = 0; c < 4; ++c) {
            int s = c * 256 + tid, row = s >> 3, gsw = ((s & 7) ^ (row & 7)) * 8;
            pa[c] = abase + (size_t)(m0 + row) * 256 + gsw;
        }
#pragma unroll
        for (int c = 0; c < 2; ++c) {
            int s = c * 256 + tid, row = s >> 3, gsw = ((s & 7) ^ (row & 7)) * 8;
            const unsigned short* k_base = whl + 131072 + (size_t)(n0 + row) * 512 + gsw;
            const unsigned short* v_base = whl + 2 * 131072 + (size_t)(n0 + row) * 512 + gsw;
            pw[0][c] = k_base;        // k hi
            pw[1][c] = k_base + 256;  // k lo
            pw[2][c] = v_base;        // v hi
            pw[3][c] = v_base + 256;  // v lo
        }
        f32x4 kacc[4][2], vacc[4][2];
#pragma unroll
        for (int i = 0; i < 4; ++i) {
            kacc[i][0] = z; kacc[i][1] = z; vacc[i][0] = z; vacc[i][1] = z;
        }
        for (int p = 0; p < 4; ++p) {
#pragma unroll
            for (int c = 0; c < 4; ++c)
                async16(&At[(c * 256 + tid) * 8], pa[c] + p * 64);
#pragma unroll
            for (int b = 0; b < 4; ++b)
#pragma unroll
                for (int c = 0; c < 2; ++c)
                    async16(Bb + b * 8192 + (c * 256 + tid) * 16, pw[b][c] + p * 64);
            __syncthreads();
#pragma unroll
            for (int kk = 0; kk < 2; ++kk) {
                short8 af[4];
#pragma unroll
                for (int f = 0; f < 4; ++f) {
                    int rowa = wm * 64 + f * 16 + l15;
                    int ka = ((kk * 4 + l4) ^ (rowa & 7)) << 4;
                    af[f] = *(const short8*)((const char*)At + rowa * 128 + ka);
                }
                short8 bf[4][2];
#pragma unroll
                for (int b = 0; b < 4; ++b)
#pragma unroll
                    for (int f = 0; f < 2; ++f) {
                        int rowb = wn * 32 + f * 16 + l15;
                        int kb2 = ((kk * 4 + l4) ^ (rowb & 7)) << 4;
                        bf[b][f] = *(const short8*)(Bb + b * 8192 + rowb * 128 + kb2);
                    }
#pragma unroll
                for (int i = 0; i < 4; ++i) {
#pragma unroll
                    for (int f = 0; f < 2; ++f) {
                        kacc[i][f] = mfma16(af[i], bf[0][f], kacc[i][f]);
                        kacc[i][f] = mfma16(af[i], bf[1][f], kacc[i][f]);
                        vacc[i][f] = mfma16(af[i], bf[2][f], vacc[i][f]);
                        vacc[i][f] = mfma16(af[i], bf[3][f], vacc[i][f]);
                    }
                }
            }
            __syncthreads();
        }
        // epilogue: BN + spike -> bf16 tiles in LDS (padded stride 272 B)
        char* kT = lds;            // 64 rows x 272 B = 17408
        char* vT = lds + 17408;    // 17408
#pragma unroll
        for (int j = 0; j < 2; ++j) {
            int cwi = wn * 32 + j * 16 + l15;         // c within 64
            int ck = 256 + n0 + cwi;                  // k-branch BN index
            int cv = 512 + n0 + cwi;                  // v-branch BN index
            float kinv = bninv[ck], ksh = bnsh[ck];
            float vinv = bninv[cv], vsh = bnsh[cv];
#pragma unroll
            for (int i = 0; i < 4; ++i) {
                int nb = wm * 64 + i * 16 + l4 * 4;
                f32x4 ka = kacc[i][j], va = vacc[i][j];
                ushort4 ku, vu;
                ku.x = bfbits(mspike(ka[0] * kinv + ksh));
                ku.y = bfbits(mspike(ka[1] * kinv + ksh));
                ku.z = bfbits(mspike(ka[2] * kinv + ksh));
                ku.w = bfbits(mspike(ka[3] * kinv + ksh));
                vu.x = bfbits(mspike(va[0] * vinv + vsh));
                vu.y = bfbits(mspike(va[1] * vinv + vsh));
                vu.z = bfbits(mspike(va[2] * vinv + vsh));
                vu.w = bfbits(mspike(va[3] * vinv + vsh));
                *(ushort4*)(kT + cwi * 272 + nb * 2) = ku;
                *(ushort4*)(vT + cwi * 272 + nb * 2) = vu;
            }
        }
        __syncthreads();
        // partial kTv over this block's 128 n: D[d2][d1] per head (wn=head)
        f32x4 pk[2];
        pk[0] = z; pk[1] = z;
#pragma unroll
        for (int ks = 0; ks < 4; ++ks) {
            short8 a = *(const short8*)(vT + (wn * 32 + wm * 16 + l15) * 272 +
                                        ks * 64 + l4 * 16);
#pragma unroll
            for (int j = 0; j < 2; ++j) {
                short8 b = *(const short8*)(kT + (wn * 32 + j * 16 + l15) * 272 +
                                            ks * 64 + l4 * 16);
                pk[j] = mfma16(a, b, pk[j]);
            }
        }
        int slice = m0 >> 7, h = c0t * 2 + wn;
        size_t pb = ((((size_t)slice * 8 + tb) * 8 + h) * 32) * 32;
#pragma unroll
        for (int j = 0; j < 2; ++j)
#pragma unroll
            for (int r = 0; r < 4; ++r) {
                int d2 = wm * 16 + l4 * 4 + r, d1 = j * 16 + l15;
                part[pb + (size_t)d2 * 32 + d1] = (_Float16)pk[j][r];
            }
    }
}

// ==== K3 (256 blocks): reduce kTv + ov + final conv + residual ==============
// block: tb = bz&7, u = bz>>3: m0 = (u>>1)*64 (n rows), cop = u&1 (c_out half)
__global__ __launch_bounds__(256, 2) void ov_conv_kernel(
    const unsigned short* __restrict__ whl,
    const unsigned short* __restrict__ sqT,
    const _Float16* __restrict__ part,
    const float* __restrict__ bninv, const float* __restrict__ bnsh,
    const float* __restrict__ tmp, float* __restrict__ outf) {
    __shared__ char lds[65536];
    char* kvt = lds;            // 256 rows (h*32+d2) x 128 B, XOR-swizzled
    char* oT = lds + 32768;     // 64 rows (n) x 512 B, XOR-swizzled
    int bz = blockIdx.x;
    int tb = bz & 7, u = bz >> 3;
    int m0 = (u >> 1) * 64, cop = u & 1;
    const int tid = threadIdx.x, lane = tid & 63, w = tid >> 6;
    const int l15 = lane & 15, l4 = lane >> 4;
    f32x4 z = {0.f, 0.f, 0.f, 0.f};

    // ---- phase A: reduce 8 slices of part -> hi/lo bf16 kvt[h*32+d2][d1hl] --
    {
        int h = tid >> 5, d2 = tid & 31;
        float sum[32];
#pragma unroll
        for (int d = 0; d < 32; ++d) sum[d] = 0.f;
#pragma unroll
        for (int s = 0; s < 8; ++s) {
            size_t pb = ((((size_t)s * 8 + tb) * 8 + h) * 32 + d2) * 32;
#pragma unroll
            for (int c = 0; c < 4; ++c) {
                half8 hv = *(const half8*)&part[pb + c * 8];
#pragma unroll
                for (int e = 0; e < 8; ++e) sum[c * 8 + e] += (float)hv[e];
            }
        }
        unsigned short hl[64];
#pragma unroll
        for (int d = 0; d < 32; ++d) {
            unsigned short hi = bfbits(sum[d]);
            __hip_bfloat16 hb = *(__hip_bfloat16*)&hi;
            hl[d] = hi;
            hl[32 + d] = bfbits(sum[d] - __bfloat162float(hb));
        }
        int row = tid;
#pragma unroll
        for (int c = 0; c < 8; ++c) {
            short8 v;
#pragma unroll
            for (int e = 0; e < 8; ++e) v[e] = (short)hl[c * 8 + e];
            *(short8*)(kvt + row * 128 + ((c * 16) ^ ((row & 7) << 4))) = v;
        }
    }
    __syncthreads();

    // ---- phase B: o rows n = m0 + w*16 + (rows), all 256 c, spike -> oT ----
    {
        f32x4 oacc[8][2];
#pragma unroll
        for (int h = 0; h < 8; ++h) { oacc[h][0] = z; oacc[h][1] = z; }
        const unsigned short* qb = sqT + (size_t)tb * CN;
#pragma unroll
        for (int h = 0; h < 8; ++h) {
            int n = m0 + w * 16 + l15;
            short8 aq = *(const short8*)&qb[(size_t)n * C_DIM + h * 32 + l4 * 8];
#pragma unroll
            for (int j = 0; j < 2; ++j) {
                int row = h * 32 + j * 16 + l15;
                short8 bhi = *(const short8*)(kvt + row * 128 +
                                              ((l4 * 16) ^ ((row & 7) << 4)));
                short8 blo = *(const short8*)(kvt + row * 128 +
                                              ((64 + l4 * 16) ^ ((row & 7) << 4)));
                oacc[h][j] = mfma16(aq, bhi, oacc[h][j]);
                oacc[h][j] = mfma16(aq, blo, oacc[h][j]);
            }
        }
#pragma unroll
        for (int h = 0; h < 8; ++h)
#pragma unroll
            for (int j = 0; j < 2; ++j)
#pragma unroll
                for (int r = 0; r < 4; ++r) {
                    int n = w * 16 + l4 * 4 + r;
                    int c = h * 32 + j * 16 + l15;
                    unsigned short sv = bfbits(mspike(SCALE * oacc[h][j][r]));
                    *(unsigned short*)(oT + n * 512 +
                                       ((c * 2) ^ ((n & 7) << 4))) = sv;
                }
    }
    __syncthreads();

    // ---- phase C: out[n 64][c_out 128] = o @ W3hi^T (K=256) + BN + resid ---
    {
        f32x4 acc[4][2];
#pragma unroll
        for (int i = 0; i < 4; ++i) { acc[i][0] = z; acc[i][1] = z; }
        const unsigned short* w3 = whl + 3 * 131072;
#pragma unroll
        for (int kc = 0; kc < 8; ++kc) {
            short8 af[4], bf[2];
#pragma unroll
            for (int i = 0; i < 4; ++i) {
                int n = i * 16 + l15;
                af[i] = *(const short8*)(oT + n * 512 +
                                         ((kc * 64 + l4 * 16) ^ ((n & 7) << 4)));
            }
#pragma unroll
            for (int j = 0; j < 2; ++j) {
                int crow = cop * 128 + (w * 2 + j) * 16 + l15;
                bf[j] = *(const short8*)&w3[(size_t)crow * 512 + kc * 32 + l4 * 8];
            }
#pragma unroll
            for (int i = 0; i < 4; ++i) {
                acc[i][0] = mfma16(af[i], bf[0], acc[i][0]);
                acc[i][1] = mfma16(af[i], bf[1], acc[i][1]);
            }
        }
#pragma unroll
        for (int j = 0; j < 2; ++j) {
            int c = cop * 128 + (w * 2 + j) * 16 + l15;
            float inv = bninv[768 + c], sh = bnsh[768 + c];
#pragma unroll
            for (int i = 0; i < 4; ++i) {
                int nb = m0 + i * 16 + l4 * 4;
                size_t off = (size_t)tb * CN + (size_t)c * N_DIM + nb;
                f32x4 a = acc[i][j];
                float4 t4 = *(const float4*)&tmp[off];
                float4 o;
                o.x = a[0] * inv + sh + t4.x;
                o.y = a[1] * inv + sh + t4.y;
                o.z = a[2] * inv + sh + t4.z;
                o.w = a[3] * inv + sh + t4.w;
                *(float4*)&outf[off] = o;
            }
        }
    }
}

extern "C" void kernel_launch(void* const* d_in, const int* in_sizes, int n_in,
                              void* d_out, int out_size, void* d_ws, size_t ws_size,
                              hipStream_t stream) {
    const float* query = (const float*)d_in[0];
    const float* qpos  = (const float*)d_in[3];
    const float* convw = (const float*)d_in[4];
    const float* convb = (const float*)d_in[5];
    const float* gam   = (const float*)d_in[6];
    const float* bet   = (const float*)d_in[7];
    const float* mn    = (const float*)d_in[8];
    const float* vr    = (const float*)d_in[9];
    float* out = (float*)d_out;

    char* ws = (char*)d_ws;
    float* tmp = (float*)ws;                                    // 8 MB
    unsigned short* sxT = (unsigned short*)(ws + (size_t)TOT * 4);  // 4 MB
    unsigned short* sqT = sxT + TOT;                            // 4 MB
    _Float16* part = (_Float16*)(sqT + TOT);                    // 1 MB
    unsigned short* whl = (unsigned short*)((char*)part + 8 * 8 * 8 * 1024 * 2);
    float* bninv = (float*)(whl + 4 * 256 * 512);
    float* bnsh = bninv + 1024;

    prep_spike_kernel<<<512, 256, 0, stream>>>(
        query, qpos, convw, convb, gam, bet, mn, vr, tmp, sxT, whl, bninv, bnsh);
    conv_qkv_kernel<<<512, 256, 0, stream>>>(whl, sxT, bninv, bnsh, sqT, part);
    ov_conv_kernel<<<256, 256, 0, stream>>>(whl, sqT, part, bninv, bnsh, tmp, out);
}